// Round 2
// baseline (77.443 us; speedup 1.0000x reference)
//
#include <hip/hip_runtime.h>

#define NB    8
#define NIN   512
#define TOUT  4096
#define ND    384
#define J4    (ND / 4)     // 96 float4 per row
#define TROWS 16           // output rows per block (kernel 2)
#define BLK   256          // threads per block (4 waves)

typedef float f32x4 __attribute__((ext_vector_type(4)));

// ---------------------------------------------------------------------------
// Kernel 1: build owner[b][t] (one block per batch, 8 blocks total).
// Scan ds[b] once, then SCATTER each token's frame range [left, cum) directly
// (max 8 writes/token) -- removes the per-frame binary search entirely.
// Tail frames [total, TOUT) get owner = -1 via a coalesced fill.
// ---------------------------------------------------------------------------
__global__ __launch_bounds__(BLK) void build_owner(const int* __restrict__ ds,
                                                   int* __restrict__ owner) {
    const int b   = blockIdx.x;
    const int tid = threadIdx.x;
    __shared__ int wsum[BLK / 64];
    __shared__ int s_total;

    const int* dsb = ds + b * NIN;
    const int a0 = dsb[2 * tid];
    const int a1 = dsb[2 * tid + 1];
    int p = a0 + a1;                     // pair sum
    const int lane = tid & 63;
    const int wid  = tid >> 6;
    #pragma unroll
    for (int off = 1; off < 64; off <<= 1) {
        int v = __shfl_up(p, off, 64);
        if (lane >= off) p += v;
    }
    if (lane == 63) wsum[wid] = p;
    __syncthreads();
    int acc = 0;
    #pragma unroll
    for (int w = 0; w < BLK / 64; ++w)
        if (w < wid) acc += wsum[w];
    p += acc;                            // inclusive cum through token 2*tid+1

    if (tid == BLK - 1) s_total = p;

    int* ob = owner + b * TOUT;
    const int incl1 = p;                 // cum[2*tid+1]
    const int incl0 = p - a1;            // cum[2*tid]
    const int left0 = incl0 - a0;        // left edge of token 2*tid
    for (int f = left0; f < incl0; ++f) ob[f] = 2 * tid;      // <= 7 iters
    for (int f = incl0; f < incl1; ++f) ob[f] = 2 * tid + 1;  // <= 7 iters
    __syncthreads();
    for (int f = s_total + tid; f < TOUT; f += BLK) ob[f] = -1;
}

// ---------------------------------------------------------------------------
// Kernel 2: barrier-free, LDS-free streaming gather-copy.
// 2048 blocks = 8 blocks/CU = 32 waves/CU (max occupancy). Per thread:
// 6 owner loads (one 64B line per block -> L1 broadcast), 6 gathered xs
// float4 loads (L2-resident, batch pinned to XCD), 6 non-temporal stores
// (keep the 50 MB write stream from evicting xs out of L2).
// ---------------------------------------------------------------------------
__global__ __launch_bounds__(BLK) void gather(const f32x4* __restrict__ xs,
                                              const int* __restrict__ owner,
                                              f32x4* __restrict__ out) {
    const int b       = blockIdx.x & 7;             // batch -> XCD pin
    const int rowbase = (blockIdx.x >> 3) * TROWS;  // first output frame
    const int tid     = threadIdx.x;

    const int*   ob   = owner + b * TOUT + rowbase;
    const f32x4* xsb  = xs + (size_t)b * NIN * J4;
    f32x4*       outb = out + ((size_t)b * TOUT + rowbase) * J4;

    constexpr int ITER = TROWS * J4 / BLK;          // 6
    int o[ITER], col[ITER];
    #pragma unroll
    for (int k = 0; k < ITER; ++k) {
        const int g = k * BLK + tid;                // 0..1535
        const int r = g / J4;                       // row 0..15 (magic-mul)
        col[k] = g - r * J4;
        o[k]   = ob[r];
    }
    f32x4 v[ITER];
    #pragma unroll
    for (int k = 0; k < ITER; ++k) {
        v[k] = (f32x4)(0.f);
        if (o[k] >= 0) v[k] = xsb[o[k] * J4 + col[k]];
    }
    #pragma unroll
    for (int k = 0; k < ITER; ++k)
        __builtin_nontemporal_store(v[k], &outb[k * BLK + tid]);
}

extern "C" void kernel_launch(void* const* d_in, const int* in_sizes, int n_in,
                              void* d_out, int out_size, void* d_ws, size_t ws_size,
                              hipStream_t stream) {
    const float* xs = (const float*)d_in[0];   // (8, 512, 384) f32
    const int*   ds = (const int*)d_in[1];     // (8, 512) int
    float* out = (float*)d_out;                // (8, 4096, 384) f32
    int*   owner = (int*)d_ws;                 // 8*4096*4 = 128 KiB in workspace

    build_owner<<<NB, BLK, 0, stream>>>(ds, owner);
    gather<<<(TOUT / TROWS) * NB, BLK, 0, stream>>>((const f32x4*)xs, owner,
                                                    (f32x4*)out);
}

// Round 3
// 74.426 us; speedup vs baseline: 1.0405x; 1.0405x over previous
//
#include <hip/hip_runtime.h>

#define NB    8
#define NIN   512
#define TOUT  4096
#define ND    384
#define J4    (ND / 4)     // 96 float4 per row
#define TROWS 16           // output rows per block
#define BLK   256          // threads per block (4 waves)

typedef float f32x4 __attribute__((ext_vector_type(4)));

// Fused length-regulator, single dispatch (R2 showed the 2-kernel split costs
// +2.5us in dispatch tax with no prelude win). Prelude is now scatter-based:
// after the block-wide scan each thread holds its two tokens' frame ranges in
// registers and scatters the token index into the block's 16-entry LDS owner
// window -- removes the 10-step LDS-dependent binary search (~1200 cyc) and
// the 512-int cum[] LDS round-trip entirely.
__global__ __launch_bounds__(BLK) void lenreg(const f32x4* __restrict__ xs,
                                              const int* __restrict__ ds,
                                              f32x4* __restrict__ out) {
    const int b       = blockIdx.x & 7;             // batch -> XCD pin
    const int rowbase = (blockIdx.x >> 3) * TROWS;  // first output frame
    const int tid     = threadIdx.x;

    __shared__ int wsum[BLK / 64];  // per-wave scan totals
    __shared__ int owner[TROWS];    // owning token per row (-1 = empty)

    if (tid < TROWS) owner[tid] = -1;

    // ---- Phase A: inclusive scan of ds[b][0..511] (each thread 2 elems) ----
    const int* dsb = ds + b * NIN;
    const int a0 = dsb[2 * tid];
    const int a1 = dsb[2 * tid + 1];
    int p = a0 + a1;                // pair sum
    const int lane = tid & 63;
    const int wid  = tid >> 6;
    #pragma unroll
    for (int off = 1; off < 64; off <<= 1) {
        int v = __shfl_up(p, off, 64);
        if (lane >= off) p += v;
    }
    if (lane == 63) wsum[wid] = p;
    __syncthreads();
    int acc = 0;
    #pragma unroll
    for (int w = 0; w < BLK / 64; ++w)
        if (w < wid) acc += wsum[w];
    p += acc;                       // inclusive cum through token 2*tid+1

    // ---- Phase B: scatter token ids into this block's owner window ----
    // Token 2*tid   covers frames [left0, incl0); token 2*tid+1 [incl0, incl1).
    const int incl1 = p;
    const int incl0 = p - a1;
    const int left0 = incl0 - a0;
    const int rowend = rowbase + TROWS;
    {
        const int lo = left0 > rowbase ? left0 : rowbase;
        const int hi = incl0 < rowend ? incl0 : rowend;
        for (int f = lo; f < hi; ++f) owner[f - rowbase] = 2 * tid;
    }
    {
        const int lo = incl0 > rowbase ? incl0 : rowbase;
        const int hi = incl1 < rowend ? incl1 : rowend;
        for (int f = lo; f < hi; ++f) owner[f - rowbase] = 2 * tid + 1;
    }
    __syncthreads();

    // ---- Phase C: 6 fully-unrolled load->store pairs, loads first ----
    const f32x4* xsb  = xs + (size_t)b * NIN * J4;
    f32x4*       outb = out + ((size_t)b * TOUT + rowbase) * J4;
    constexpr int ITER = TROWS * J4 / BLK;          // 6
    f32x4 v[ITER];
    #pragma unroll
    for (int k = 0; k < ITER; ++k) {
        const int g = k * BLK + tid;                // 0..1535
        const int r = g / J4;                       // row 0..15 (magic-mul)
        const int o = owner[r];
        v[k] = (f32x4)(0.f);
        if (o >= 0) v[k] = xsb[o * J4 + (g - r * J4)];
    }
    #pragma unroll
    for (int k = 0; k < ITER; ++k)
        outb[k * BLK + tid] = v[k];
}

extern "C" void kernel_launch(void* const* d_in, const int* in_sizes, int n_in,
                              void* d_out, int out_size, void* d_ws, size_t ws_size,
                              hipStream_t stream) {
    const float* xs = (const float*)d_in[0];   // (8, 512, 384) f32
    const int*   ds = (const int*)d_in[1];     // (8, 512) int
    float* out = (float*)d_out;                // (8, 4096, 384) f32

    // 1D grid: low 3 bits = batch (XCD slot), high bits = row tile
    lenreg<<<(TOUT / TROWS) * NB, BLK, 0, stream>>>((const f32x4*)xs, ds,
                                                    (f32x4*)out);
}